// Round 8
// baseline (636.030 us; speedup 1.0000x reference)
//
#include <hip/hip_runtime.h>
#include <hip/hip_bf16.h>
#include <cstdint>

#define BB 128
#define LL 256
#define DD 300
#define HH 512
#define TOUT 511
#define NGATE 2560   // 5*H

typedef __attribute__((ext_vector_type(8))) short bf16x8;
typedef __attribute__((ext_vector_type(4))) float f32x4;

// fast transcendentals: v_rcp_f32 + v_exp_f32 (exp2)
__device__ __forceinline__ float rcpf(float x){ return __builtin_amdgcn_rcpf(x); }
__device__ __forceinline__ float ex2f(float x){ return __builtin_amdgcn_exp2f(x); }
__device__ __forceinline__ float sigf(float x){ return rcpf(1.0f + ex2f(x * -1.44269504f)); }
__device__ __forceinline__ float tanh_fast(float x){ return 1.0f - 2.0f*rcpf(ex2f(x * 2.88539008f) + 1.0f); }

__device__ __forceinline__ void load_lds16(const void* g, void* l) {
  __builtin_amdgcn_global_load_lds(
      (const __attribute__((address_space(1))) unsigned int*)g,
      (__attribute__((address_space(3))) unsigned int*)l, 16, 0, 0);
}

#define VMWAIT(n) asm volatile("s_waitcnt vmcnt(" #n ")" ::: "memory")

// ---- transpose+convert: src f32 [Ksrc][2560] -> dst bf16 [2560][Kdst]
__global__ __launch_bounds__(256) void transpose_cvt(const float* __restrict__ src,
    __hip_bfloat16* __restrict__ dst, int Ksrc, int Kdst, int koff)
{
  __shared__ float t[64][65];
  const int tid = threadIdx.x;
  const int k0 = blockIdx.x * 64;
  const int n0 = blockIdx.y * 64;
  #pragma unroll
  for (int p = 0; p < 16; ++p) {
    int lin = p*256 + tid;
    int ki = lin >> 6, nj = lin & 63;
    t[ki][nj] = (k0 + ki < Ksrc) ? src[(size_t)(k0+ki)*NGATE + n0 + nj] : 0.f;
  }
  __syncthreads();
  #pragma unroll
  for (int p = 0; p < 16; ++p) {
    int lin = p*256 + tid;
    int ni = lin >> 6, kj = lin & 63;
    dst[(size_t)(n0+ni)*Kdst + koff + k0 + kj] = __float2bfloat16(t[kj][ni]);
  }
}

// ---- embedding gather + cvt: A0 bf16 [32768][320]
__global__ void embed_cvt(const int* __restrict__ tok, const float* __restrict__ emb,
                          __hip_bfloat16* __restrict__ A0)
{
  int k = blockIdx.x * 64 + threadIdx.x;
  int r = blockIdx.y * 4 + threadIdx.y;
  int tk = tok[r];
  float v = (k < DD) ? emb[(size_t)tk*DD + k] : 0.f;
  A0[(size_t)r*320 + k] = __float2bfloat16(v);
}

// ======== BIG-LEVEL kernel: A-frags DIRECT FROM GLOBAL, B-only LDS =========
// BM=256, BK=64, 8 waves = 2(m: 128 rows)x4(n: 16 h-cols). acc[8][5] (160 VGPR).
// Per K-tile per wave: 16 a-loads (global, 16B contiguous/lane = exact MFMA frag),
// 10 b ds_reads, 5 staging issues. MFMA:LDS cycle ratio ~2.4 (was 0.9 in R7).
// XCD co-location: panel p's 8 strips all on XCD (p&7), back-to-back.
__global__ __launch_bounds__(512, 2) void gemm_big(
    const __hip_bfloat16* __restrict__ A, const __hip_bfloat16* __restrict__ Wt,
    int K, const float* __restrict__ bias, const float* __restrict__ cprev,
    float* __restrict__ out, __hip_bfloat16* __restrict__ hout, float* __restrict__ cout,
    int lkshift, int sc)
{
  constexpr int BUFS = 40960;         // B tile: 320 rows x 64 k bf16
  __shared__ __align__(16) char lds[2*BUFS];

  const int tid  = threadIdx.x;
  const int lane = tid & 63;
  const int wid  = tid >> 6;
  const int wm   = wid >> 2;          // 0..1 (128-row half)
  const int wn   = wid & 3;           // 0..3 (16 h-col strip)
  const int bid  = blockIdx.x;
  const int m    = (bid & 7) + ((bid >> 6) << 3);
  const int s    = (bid >> 3) & 7;
  const int r0   = m * 256;
  const int n0   = s * 64;
  const size_t rowK = (size_t)K * 2;

  // B staging: 40 x 1KB issues, 5 per wave. lane l of issue gi:
  //   LDS row c = gi*8 + (l>>3), chunk cw = l&7 (linear dest)
  //   source k-chunk = cw ^ (c&7)  (involution; read side applies same XOR)
  unsigned boff[5];
  #pragma unroll
  for (int i = 0; i < 5; ++i) {
    int gi = wid*5 + i;
    int c  = gi*8 + (lane >> 3);
    int kc = (lane & 7) ^ ((lane >> 3) & 7);
    int grow = (c >> 6)*512 + n0 + (c & 63);
    boff[i] = (unsigned)((size_t)grow*rowK) + kc*16;
  }
  const int ldst0 = (wid*5)*1024 + lane*16;

  // A-frag base: lane holds row (lane&15), k-chunk (lane>>4) of each 16x32 frag
  const unsigned aoff0 = (unsigned)((size_t)(r0 + wm*128 + (lane & 15))*rowK) + (lane >> 4)*16;
  const unsigned mfstride = (unsigned)(rowK * 16);

  f32x4 acc[8][5];
  #pragma unroll
  for (int mf = 0; mf < 8; ++mf)
    #pragma unroll
    for (int g5 = 0; g5 < 5; ++g5)
      acc[mf][g5] = (f32x4){0.f,0.f,0.f,0.f};

  const int nt = K >> 6;
  auto stage = [&](int buf, int t){
    char* base = lds + buf*BUFS + ldst0;
    const unsigned kb = (unsigned)t*128;
    #pragma unroll
    for (int i = 0; i < 5; ++i)
      load_lds16((const char*)Wt + boff[i] + kb, base + i*1024);
  };

  stage(0, 0);
  int cur = 0;
  for (int t = 0; t < nt; ++t) {
    if (t == 0) VMWAIT(0); else VMWAIT(5);
    __builtin_amdgcn_s_barrier();       // B(t) landed; all waves done reading buf^1
    if (t + 1 < nt) stage(cur ^ 1, t + 1);
    __builtin_amdgcn_sched_barrier(0);  // pin stage glds before a-loads (vmcnt FIFO)

    const char* Bb = lds + cur*BUFS;
    #pragma unroll
    for (int ks = 0; ks < 2; ++ks) {
      const char* ab = (const char*)A + aoff0 + (unsigned)t*128 + ks*64;
      bf16x8 a[8], b[5];
      #pragma unroll
      for (int mf = 0; mf < 8; ++mf)
        a[mf] = *(const bf16x8*)(ab + mf*mfstride);
      #pragma unroll
      for (int g5 = 0; g5 < 5; ++g5) {
        int c = g5*64 + wn*16 + (lane & 15);
        int q = (ks*4 + (lane >> 4)) ^ (c & 7);
        b[g5] = *(const bf16x8*)(Bb + c*128 + q*16);
      }
      __builtin_amdgcn_s_setprio(1);
      #pragma unroll
      for (int mf = 0; mf < 8; ++mf)
        #pragma unroll
        for (int g5 = 0; g5 < 5; ++g5)
          acc[mf][g5] = __builtin_amdgcn_mfma_f32_16x16x32_bf16(a[mf], b[g5], acc[mf][g5], 0, 0, 0);
      __builtin_amdgcn_s_setprio(0);
    }
    cur ^= 1;
  }

  // epilogue: fused LSTM cell (fast rcp/exp2)
  const int Lmask = (1 << lkshift) - 1;
  const int jg = n0 + wn*16 + (lane & 15);
  float bia[5];
  #pragma unroll
  for (int g5 = 0; g5 < 5; ++g5) bia[g5] = bias[g5*HH + jg];
  #pragma unroll
  for (int mf = 0; mf < 8; ++mf) {
    #pragma unroll
    for (int v = 0; v < 4; ++v) {
      int rr = r0 + wm*128 + mf*16 + (lane >> 4)*4 + v;
      float gi  = acc[mf][0][v] + bia[0];
      float gfl = acc[mf][1][v] + bia[1];
      float gfr = acc[mf][2][v] + bia[2];
      float go  = acc[mf][3][v] + bia[3];
      float gu  = acc[mf][4][v] + bia[4];
      float cl = 0.f, cr = 0.f;
      if (cprev) {
        cl = cprev[(size_t)(2*rr)*HH + jg];
        cr = cprev[(size_t)(2*rr)*HH + HH + jg];
      }
      float cc = sigf(gi)*tanh_fast(gu) + sigf(gfl)*cl + sigf(gfr)*cr;
      float hh = sigf(go)*tanh_fast(cc);
      int b = rr >> lkshift;
      int t = rr & Lmask;
      out[((size_t)b*TOUT + sc + t)*HH + jg] = hh;
      hout[(size_t)rr*HH + jg] = __float2bfloat16(hh);
      cout[(size_t)rr*HH + jg] = cc;
    }
  }
}

// ======== TAIL kernel (R7 V_A): BM=128, BK=32, 56KB LDS, 2 blocks/CU ========
__global__ __launch_bounds__(512, 4) void gemm_cell(
    const __hip_bfloat16* __restrict__ A, const __hip_bfloat16* __restrict__ Wt,
    int K, const float* __restrict__ bias, const float* __restrict__ cprev,
    float* __restrict__ out, __hip_bfloat16* __restrict__ hout, float* __restrict__ cout,
    int lkshift, int sc, int numM)
{
  constexpr int BUFS = 28672;
  __shared__ __align__(16) char lds[2*BUFS];

  const int tid  = threadIdx.x;
  const int lane = tid & 63;
  const int wid  = tid >> 6;
  const int wm   = wid >> 2;
  const int wn   = wid & 3;
  const int bid  = blockIdx.x;
  int m, s;
  if (numM >= 8) { m = (bid & 7) + ((bid >> 6) << 3); s = (bid >> 3) & 7; }
  else           { m = bid % numM;  s = bid / numM; }
  const int r0   = m * 128;
  const int n0   = s * 64;
  const size_t rowK = (size_t)K * 2;

  const char* gsrc[4];
  int gi0 = (wid < 4) ? wid*4 : 16 + (wid-4)*3;
  #pragma unroll
  for (int i = 0; i < 4; ++i) {
    int gi = gi0 + i;
    int row = (gi < 8) ? gi*16 + (lane >> 2) : (gi-8)*16 + (lane >> 2);
    int cg = (lane & 3) ^ ((row >> 1) & 3);
    if (gi < 8) {
      gsrc[i] = (const char*)A + (size_t)(r0 + row)*rowK + cg*16;
    } else {
      int grow = (row >> 6)*512 + n0 + (row & 63);
      gsrc[i] = (const char*)Wt + (size_t)grow*rowK + cg*16;
    }
  }
  const int ldst0 = gi0*1024 + lane*16;

  f32x4 acc[4][5];
  #pragma unroll
  for (int mf = 0; mf < 4; ++mf)
    #pragma unroll
    for (int g5 = 0; g5 < 5; ++g5)
      acc[mf][g5] = (f32x4){0.f,0.f,0.f,0.f};

  const int nk = K >> 5;
  auto stage = [&](int buf, int kt){
    char* base = lds + buf*BUFS + ldst0;
    const size_t kb = (size_t)kt*64;
    if (wid < 4) {
      #pragma unroll
      for (int i = 0; i < 4; ++i) load_lds16(gsrc[i] + kb, base + i*1024);
    } else {
      #pragma unroll
      for (int i = 0; i < 3; ++i) load_lds16(gsrc[i] + kb, base + i*1024);
    }
  };

  stage(0, 0);
  int cur = 0;
  for (int kt = 0; kt < nk; ++kt) {
    if (kt + 1 < nk) {
      stage(cur ^ 1, kt + 1);
      if (wid < 4) VMWAIT(4); else VMWAIT(3);
    } else {
      VMWAIT(0);
    }
    __builtin_amdgcn_s_barrier();

    const char* Ab = lds + cur*BUFS;
    const char* Bb = Ab + 8192;
    const int q = lane >> 4;
    bf16x8 b[5];
    #pragma unroll
    for (int g5 = 0; g5 < 5; ++g5) {
      int c = g5*64 + wn*16 + (lane & 15);
      b[g5] = *(const bf16x8*)(Bb + c*64 + ((q ^ ((c >> 1) & 3))*16));
    }
    __builtin_amdgcn_s_setprio(1);
    #pragma unroll
    for (int mf = 0; mf < 4; ++mf) {
      int r = wm*64 + mf*16 + (lane & 15);
      bf16x8 av = *(const bf16x8*)(Ab + r*64 + ((q ^ ((r >> 1) & 3))*16));
      #pragma unroll
      for (int g5 = 0; g5 < 5; ++g5)
        acc[mf][g5] = __builtin_amdgcn_mfma_f32_16x16x32_bf16(av, b[g5], acc[mf][g5], 0, 0, 0);
    }
    __builtin_amdgcn_s_setprio(0);
    __builtin_amdgcn_s_barrier();
    cur ^= 1;
  }

  const int Lmask = (1 << lkshift) - 1;
  const int jg = n0 + wn*16 + (lane & 15);
  float bia[5];
  #pragma unroll
  for (int g5 = 0; g5 < 5; ++g5) bia[g5] = bias[g5*HH + jg];
  #pragma unroll
  for (int mf = 0; mf < 4; ++mf) {
    #pragma unroll
    for (int v = 0; v < 4; ++v) {
      int rr = r0 + wm*64 + mf*16 + (lane >> 4)*4 + v;
      float gi  = acc[mf][0][v] + bia[0];
      float gfl = acc[mf][1][v] + bia[1];
      float gfr = acc[mf][2][v] + bia[2];
      float go  = acc[mf][3][v] + bia[3];
      float gu  = acc[mf][4][v] + bia[4];
      float cl = 0.f, cr = 0.f;
      if (cprev) {
        cl = cprev[(size_t)(2*rr)*HH + jg];
        cr = cprev[(size_t)(2*rr)*HH + HH + jg];
      }
      float cc = sigf(gi)*tanh_fast(gu) + sigf(gfl)*cl + sigf(gfr)*cr;
      float hh = sigf(go)*tanh_fast(cc);
      int b = rr >> lkshift;
      int t = rr & Lmask;
      out[((size_t)b*TOUT + sc + t)*HH + jg] = hh;
      hout[(size_t)rr*HH + jg] = __float2bfloat16(hh);
      cout[(size_t)rr*HH + jg] = cc;
    }
  }
}

extern "C" void kernel_launch(void* const* d_in, const int* in_sizes, int n_in,
                              void* d_out, int out_size, void* d_ws, size_t ws_size,
                              hipStream_t stream) {
  (void)in_sizes; (void)n_in; (void)out_size; (void)ws_size;
  const int*   tok  = (const int*)d_in[0];
  const float* emb  = (const float*)d_in[1];
  const float* Wx   = (const float*)d_in[2];
  const float* Ul   = (const float*)d_in[3];
  const float* Ur   = (const float*)d_in[4];
  const float* bias = (const float*)d_in[5];
  float* out = (float*)d_out;

  char* ws = (char*)d_ws;
  size_t off = 0;
  __hip_bfloat16* Wb0t = (__hip_bfloat16*)(ws + off); off += (size_t)NGATE*320*2;
  __hip_bfloat16* Wb1t = (__hip_bfloat16*)(ws + off); off += (size_t)NGATE*1024*2;
  __hip_bfloat16* hA   = (__hip_bfloat16*)(ws + off); off += (size_t)32768*HH*2;
  __hip_bfloat16* hB   = (__hip_bfloat16*)(ws + off); off += (size_t)16384*HH*2;
  float*          cA   = (float*)(ws + off);          off += (size_t)32768*HH*4;
  float*          cB   = (float*)(ws + off);          off += (size_t)16384*HH*4;
  __hip_bfloat16* A0   = (__hip_bfloat16*)cB;   // alias: A0 dead before cB first written

  transpose_cvt<<<dim3(5, 40), 256, 0, stream>>>(Wx, Wb0t, DD, 320, 0);
  transpose_cvt<<<dim3(8, 40), 256, 0, stream>>>(Ul, Wb1t, HH, 1024, 0);
  transpose_cvt<<<dim3(8, 40), 256, 0, stream>>>(Ur, Wb1t, HH, 1024, 512);
  embed_cvt<<<dim3(5, 8192), dim3(64,4), 0, stream>>>(tok, emb, A0);

  // level 0: M=32768, K=320 (nt=5)
  gemm_big<<<(32768/256)*8, 512, 0, stream>>>(A0, Wb0t, 320, bias, nullptr,
                                              out, hA, cA, 8, 0);
  // levels 1..8
  for (int k = 1; k <= 8; ++k) {
    int M = 32768 >> k;
    int sc = HH - (HH >> k);
    const __hip_bfloat16* Ain = (k & 1) ? hA : hB;
    __hip_bfloat16*       hO  = (k & 1) ? hB : hA;
    const float*          cI  = (k & 1) ? cA : cB;
    float*                cO  = (k & 1) ? cB : cA;
    if (M >= 8192) {
      gemm_big<<<(M/256)*8, 512, 0, stream>>>(Ain, Wb1t, 1024, bias, cI,
                                              out, hO, cO, 8 - k, sc);
    } else {
      int numM = M / 128;
      gemm_cell<<<numM*8, 512, 0, stream>>>(Ain, Wb1t, 1024, bias, cI,
                                            out, hO, cO, 8 - k, sc, numM);
    }
  }
}